// Round 7
// baseline (3801.229 us; speedup 1.0000x reference)
//
#include <hip/hip_runtime.h>
#include <hip/hip_fp16.h>

#define N_NODES 100000
#define EMB_DIM 64
#define N_EDGES 3200000
#define N_LAYERS 3

#define SCAN_BLOCK 512
#define N_SCAN_BLOCKS ((N_NODES + SCAN_BLOCK - 1) / SCAN_BLOCK)   // 196

// Bins: 128 rows each. Records grouped by bin feed the fused bin-SpMM directly.
#define ABINROWS 128
#define NBINS ((N_NODES + ABINROWS - 1) / ABINROWS)   // 782
#define ACHUNK 4096
#define NCHUNKS ((N_EDGES + ACHUNK - 1) / ACHUNK)     // 782
#define BC_WGS 256
#define BC_CHUNK ((N_EDGES + BC_WGS - 1) / BC_WGS)    // 12500
#define SPMM_GRID 1568   // 8 XCD slots x 196; (bin, dim-half) decoded from blockIdx

// d_out layout: mean [N_NODES*64] first, then stacked [N_NODES*4*64]
// stacked[n][l][d] at n*256 + l*64 + d

__device__ __forceinline__ unsigned short f32_to_bf16_rtn(float f) {
    unsigned u = __float_as_uint(f);
    unsigned r = u + 0x7FFFu + ((u >> 16) & 1u);
    return (unsigned short)(r >> 16);
}
__device__ __forceinline__ float bf16_to_f32(unsigned short h) {
    return __uint_as_float(((unsigned)h) << 16);
}

// ---------- bin-level counting ----------
// 256 WGs, LDS-private histogram -> ~200K merged global atomics total.

__global__ void __launch_bounds__(256) bin_count(const int* __restrict__ rows,
                                                 int* __restrict__ binCounts) {
    __shared__ int h[NBINS];
    int t = threadIdx.x;
    for (int i = t; i < NBINS; i += 256) h[i] = 0;
    __syncthreads();
    int base = blockIdx.x * BC_CHUNK;
    int n = N_EDGES - base; if (n > BC_CHUNK) n = BC_CHUNK;
    for (int i = t; i < n; i += 256) atomicAdd(&h[rows[base + i] >> 7], 1);
    __syncthreads();
    for (int i = t; i < NBINS; i += 256) {
        int c = h[i];
        if (c) atomicAdd(&binCounts[i], c);
    }
}

__global__ void __launch_bounds__(1024) bin_scan(const int* __restrict__ binCounts,
                                                 int* __restrict__ binPtr) {
    __shared__ int sm[1024];
    int t = threadIdx.x;
    int v = (t < NBINS) ? binCounts[t] : 0;
    sm[t] = v;
    __syncthreads();
    for (int off = 1; off < 1024; off <<= 1) {
        int u = (t >= off) ? sm[t - off] : 0;
        __syncthreads();
        sm[t] += u;
        __syncthreads();
    }
    if (t < NBINS) binPtr[t + 1] = sm[t];
    if (t == 0) binPtr[0] = 0;
}

// ---------- sort2: two-pass bin partition, no LDS staging, no scan ----------
// Pass 1: LDS histogram of this chunk. Reserve one contiguous global run per
// non-empty bin (1 atomic each). Pass 2: re-read edges (L2-hot), write each
// record at runBase + LDS cursor -> run-dense lines, WG-owned.
// Packed edge: col (17 bits) << 15 | fp16(val) low 15 bits (val>=0 so sign=0).

__global__ void __launch_bounds__(256) build_sort2(const int* __restrict__ rows,
                                                   const int* __restrict__ cols,
                                                   const float* __restrict__ vals,
                                                   const int* __restrict__ binPtr,
                                                   int* __restrict__ bucketFill,
                                                   uint2* __restrict__ records) {
    __shared__ int binCnt[NBINS];
    __shared__ int binCur[NBINS];
    __shared__ int binG[NBINS];
    int base = blockIdx.x * ACHUNK;
    int n = N_EDGES - base; if (n > ACHUNK) n = ACHUNK;
    int t = threadIdx.x;

    for (int i = t; i < NBINS; i += 256) { binCnt[i] = 0; binCur[i] = 0; }
    __syncthreads();
    for (int i = t; i < n; i += 256) atomicAdd(&binCnt[rows[base + i] >> 7], 1);
    __syncthreads();
    for (int b = t; b < NBINS; b += 256) {
        int c = binCnt[b];
        if (c) binG[b] = binPtr[b] + atomicAdd(&bucketFill[b], c);
    }
    __syncthreads();
    for (int i = t; i < n; i += 256) {
        int e = base + i;
        int r = rows[e];
        int b = r >> 7;
        unsigned hb = __half_as_ushort(__float2half(vals[e]));
        unsigned pk = (((unsigned)cols[e]) << 15) | (hb & 0x7FFFu);
        int pos = binG[b] + atomicAdd(&binCur[b], 1);
        records[pos] = make_uint2((unsigned)r, pk);
    }
}

// ---------- emb -> bf16 mirror ----------
__global__ void emb_to_bf16(const float* __restrict__ emb, ushort4* __restrict__ mirror) {
    int t = blockIdx.x * blockDim.x + threadIdx.x;   // [0, N_NODES*16)
    if (t >= N_NODES * 16) return;
    float4 v = ((const float4*)emb)[t];
    ushort4 o;
    o.x = f32_to_bf16_rtn(v.x); o.y = f32_to_bf16_rtn(v.y);
    o.z = f32_to_bf16_rtn(v.z); o.w = f32_to_bf16_rtn(v.w);
    mirror[t] = o;
}

// ---------- fused bin-SpMM ----------
// WG = (bin of 128 rows, dim-half of 32). 8 lanes/record, each lane gathers
// 8 B of the 64 B mirror half-line and does 4 ds_add_f32 into the padded
// LDS accumulator (stride 33 floats -> bank spread by random row).
// blockIdx -> XCD (b&7, round-robin heuristic): XCDs 0-3 take half 0,
// 4-7 take half 1 -> per-XCD gather working set = 6.4 MB.

__device__ __forceinline__ bool spmm_bin_decode(int b, int& bin, int& hf) {
    int xcd = b & 7;
    hf = xcd >> 2;
    bin = (b >> 3) * 4 + (xcd & 3);
    return bin < NBINS;
}

__device__ __forceinline__ void spmm_bin_accum(int bin, int hf,
                                               const int* __restrict__ binPtr,
                                               const uint2* __restrict__ records,
                                               const unsigned short* __restrict__ srcMirror,
                                               float* lacc) {
    int t = threadIdx.x;
    for (int i = t; i < ABINROWS * 33; i += 256) lacc[i] = 0.f;
    __syncthreads();
    int r0 = bin * ABINROWS;
    int beg = binPtr[bin];
    int end = binPtr[bin + 1];
    int s = t & 7;
    int hoff = hf * 32 + s * 4;
    for (int i = beg + (t >> 3); i < end; i += 32) {
        uint2 rec = records[i];
        int lr = (int)rec.x - r0;
        float v = __half2float(__ushort_as_half((unsigned short)(rec.y & 0x7FFFu)));
        ushort4 m = *(const ushort4*)(srcMirror + (size_t)(rec.y >> 15) * 64 + hoff);
        float* ap = lacc + lr * 33 + s * 4;
        atomicAdd(ap + 0, v * bf16_to_f32(m.x));
        atomicAdd(ap + 1, v * bf16_to_f32(m.y));
        atomicAdd(ap + 2, v * bf16_to_f32(m.z));
        atomicAdd(ap + 3, v * bf16_to_f32(m.w));
    }
    __syncthreads();
}

__global__ void __launch_bounds__(256) spmm_bin_mid(const int* __restrict__ binPtr,
                                                    const uint2* __restrict__ records,
                                                    const unsigned short* __restrict__ srcMirror,
                                                    float* __restrict__ dstStacked,   // stacked + l*64
                                                    unsigned short* __restrict__ dstMirror) {
    __shared__ float lacc[ABINROWS * 33];
    int bin, hf;
    if (!spmm_bin_decode(blockIdx.x, bin, hf)) return;
    spmm_bin_accum(bin, hf, binPtr, records, srcMirror, lacc);
    int r0 = bin * ABINROWS;
    int nr = N_NODES - r0; if (nr > ABINROWS) nr = ABINROWS;
    for (int idx = threadIdx.x; idx < nr * 8; idx += 256) {
        int lr = idx >> 3, c = idx & 7;
        float* ap = lacc + lr * 33 + c * 4;
        float4 vv = make_float4(ap[0], ap[1], ap[2], ap[3]);
        size_t n = (size_t)(r0 + lr);
        *(float4*)(dstStacked + n * 256 + hf * 32 + c * 4) = vv;
        ushort4 o;
        o.x = f32_to_bf16_rtn(vv.x); o.y = f32_to_bf16_rtn(vv.y);
        o.z = f32_to_bf16_rtn(vv.z); o.w = f32_to_bf16_rtn(vv.w);
        *(ushort4*)(dstMirror + n * 64 + hf * 32 + c * 4) = o;
    }
}

// Last layer: fuse layer-0 copy, layer-3 write, and 4-layer mean.
__global__ void __launch_bounds__(256) spmm_bin_last(const int* __restrict__ binPtr,
                                                     const uint2* __restrict__ records,
                                                     const unsigned short* __restrict__ srcMirror,
                                                     const float* __restrict__ emb,
                                                     float* __restrict__ stacked,
                                                     float* __restrict__ meanOut) {
    __shared__ float lacc[ABINROWS * 33];
    int bin, hf;
    if (!spmm_bin_decode(blockIdx.x, bin, hf)) return;
    spmm_bin_accum(bin, hf, binPtr, records, srcMirror, lacc);
    int r0 = bin * ABINROWS;
    int nr = N_NODES - r0; if (nr > ABINROWS) nr = ABINROWS;
    for (int idx = threadIdx.x; idx < nr * 8; idx += 256) {
        int lr = idx >> 3, c = idx & 7;
        float* ap = lacc + lr * 33 + c * 4;
        float4 d3 = make_float4(ap[0], ap[1], ap[2], ap[3]);
        size_t n = (size_t)(r0 + lr);
        int doff = hf * 32 + c * 4;
        size_t soff = n * 256 + doff;
        float4 a  = *(const float4*)(emb + n * 64 + doff);
        float4 b1 = *(const float4*)(stacked + soff + 64);
        float4 c2 = *(const float4*)(stacked + soff + 128);
        *(float4*)(stacked + soff) = a;            // layer 0
        *(float4*)(stacked + soff + 192) = d3;     // layer 3
        float4 s;
        s.x = 0.25f * (a.x + b1.x + c2.x + d3.x);
        s.y = 0.25f * (a.y + b1.y + c2.y + d3.y);
        s.z = 0.25f * (a.z + b1.z + c2.z + d3.z);
        s.w = 0.25f * (a.w + b1.w + c2.w + d3.w);
        *(float4*)(meanOut + n * 64 + doff) = s;
    }
}

// ---------- f32 fallback path (per-row CSR, unchanged) ----------

__global__ void count_rows(const int* __restrict__ rows, int* __restrict__ counts) {
    int e = blockIdx.x * blockDim.x + threadIdx.x;
    if (e >= N_EDGES) return;
    atomicAdd(&counts[rows[e]], 1);
}

__global__ void __launch_bounds__(SCAN_BLOCK) scan_phase1(const int* __restrict__ counts,
                                                          int* __restrict__ blockSums) {
    __shared__ int sm[SCAN_BLOCK];
    int idx = blockIdx.x * SCAN_BLOCK + threadIdx.x;
    int v = (idx < N_NODES) ? counts[idx] : 0;
    sm[threadIdx.x] = v;
    __syncthreads();
    for (int off = SCAN_BLOCK / 2; off > 0; off >>= 1) {
        if (threadIdx.x < off) sm[threadIdx.x] += sm[threadIdx.x + off];
        __syncthreads();
    }
    if (threadIdx.x == 0) blockSums[blockIdx.x] = sm[0];
}

__global__ void __launch_bounds__(256) scan_phase2(const int* __restrict__ blockSums,
                                                   int* __restrict__ blockOffs,
                                                   int* __restrict__ row_ptr) {
    __shared__ int sm[256];
    int t = threadIdx.x;
    int v = (t < N_SCAN_BLOCKS) ? blockSums[t] : 0;
    sm[t] = v;
    __syncthreads();
    for (int off = 1; off < 256; off <<= 1) {
        int u = (t >= off) ? sm[t - off] : 0;
        __syncthreads();
        sm[t] += u;
        __syncthreads();
    }
    if (t < N_SCAN_BLOCKS) blockOffs[t] = (t == 0) ? 0 : sm[t - 1];
    if (t == 255) row_ptr[N_NODES] = sm[255];
}

__global__ void __launch_bounds__(SCAN_BLOCK) scan_phase3(const int* __restrict__ counts,
                                                          const int* __restrict__ blockOffs,
                                                          int* __restrict__ row_ptr) {
    __shared__ int sm[SCAN_BLOCK];
    int idx = blockIdx.x * SCAN_BLOCK + threadIdx.x;
    int t = threadIdx.x;
    int v = (idx < N_NODES) ? counts[idx] : 0;
    sm[t] = v;
    __syncthreads();
    for (int off = 1; off < SCAN_BLOCK; off <<= 1) {
        int u = (t >= off) ? sm[t - off] : 0;
        __syncthreads();
        sm[t] += u;
        __syncthreads();
    }
    if (idx < N_NODES) row_ptr[idx] = blockOffs[blockIdx.x] + sm[t] - v;
}

__global__ void scatter_edges_int2(const int* __restrict__ rows, const int* __restrict__ cols,
                                   const float* __restrict__ vals,
                                   const int* __restrict__ row_ptr, int* __restrict__ fill,
                                   int2* __restrict__ s_colval) {
    int e = blockIdx.x * blockDim.x + threadIdx.x;
    if (e >= N_EDGES) return;
    int r = rows[e];
    int pos = row_ptr[r] + atomicAdd(&fill[r], 1);
    int2 p; p.x = cols[e]; p.y = __float_as_int(vals[e]);
    s_colval[pos] = p;
}

__global__ void __launch_bounds__(256) spmm_gather_f32(const int* __restrict__ row_ptr,
                                                       const int2* __restrict__ s_colval,
                                                       const float* __restrict__ src, int srcStride,
                                                       float* __restrict__ dst) {
    int wave = (blockIdx.x * blockDim.x + threadIdx.x) >> 6;
    if (wave >= N_NODES) return;
    int lane = threadIdx.x & 63;
    int g = lane >> 4, j = lane & 15;
    int beg = row_ptr[wave], end = row_ptr[wave + 1];
    float4 acc = make_float4(0.f, 0.f, 0.f, 0.f);
    int e = beg + g;
    for (; e + 4 < end; e += 8) {
        int2 p0 = s_colval[e], p1 = s_colval[e + 4];
        float v0 = __int_as_float(p0.y), v1 = __int_as_float(p1.y);
        float4 m0 = *(const float4*)(src + (size_t)p0.x * srcStride + j * 4);
        float4 m1 = *(const float4*)(src + (size_t)p1.x * srcStride + j * 4);
        acc.x += v0 * m0.x + v1 * m1.x; acc.y += v0 * m0.y + v1 * m1.y;
        acc.z += v0 * m0.z + v1 * m1.z; acc.w += v0 * m0.w + v1 * m1.w;
    }
    for (; e < end; e += 4) {
        int2 p = s_colval[e];
        float v = __int_as_float(p.y);
        float4 m = *(const float4*)(src + (size_t)p.x * srcStride + j * 4);
        acc.x += v * m.x; acc.y += v * m.y; acc.z += v * m.z; acc.w += v * m.w;
    }
    acc.x += __shfl_xor(acc.x, 16); acc.y += __shfl_xor(acc.y, 16);
    acc.z += __shfl_xor(acc.z, 16); acc.w += __shfl_xor(acc.w, 16);
    acc.x += __shfl_xor(acc.x, 32); acc.y += __shfl_xor(acc.y, 32);
    acc.z += __shfl_xor(acc.z, 32); acc.w += __shfl_xor(acc.w, 32);
    if (lane < 16)
        *(float4*)(dst + (size_t)wave * 256 + j * 4) = acc;
}

__global__ void mean_layers(const float* __restrict__ emb,
                            float* __restrict__ stacked,
                            float* __restrict__ meanOut) {
    int t = blockIdx.x * blockDim.x + threadIdx.x;   // [0, N_NODES*16)
    if (t >= N_NODES * 16) return;
    int n = t >> 4;
    int j = t & 15;
    float4* base = (float4*)stacked + (size_t)n * 64;
    float4 a = ((const float4*)emb)[t];
    float4 b = base[16 + j];
    float4 c = base[32 + j];
    float4 d = base[48 + j];
    base[j] = a;
    float4 s;
    s.x = 0.25f * (a.x + b.x + c.x + d.x);
    s.y = 0.25f * (a.y + b.y + c.y + d.y);
    s.z = 0.25f * (a.z + b.z + c.z + d.z);
    s.w = 0.25f * (a.w + b.w + c.w + d.w);
    ((float4*)meanOut)[t] = s;
}

// ---------- last fallback: atomic scatter ----------

__global__ void init_stacked_full(const float* __restrict__ emb, float* __restrict__ stacked) {
    int t = blockIdx.x * blockDim.x + threadIdx.x;
    if (t >= N_NODES * 64) return;
    int n = t >> 6, j = t & 63;
    float4 v = (j < 16) ? ((const float4*)emb)[n * 16 + j] : make_float4(0.f, 0.f, 0.f, 0.f);
    ((float4*)stacked)[n * 64 + j] = v;
}

__global__ void spmm_atomic(const int* __restrict__ rows, const int* __restrict__ cols,
                            const float* __restrict__ vals, float* __restrict__ stacked,
                            int lprev) {
    int t = blockIdx.x * blockDim.x + threadIdx.x;
    int e = t >> 4, j = t & 15;
    if (e >= N_EDGES) return;
    int r = rows[e], c = cols[e];
    float v = vals[e];
    const float4* src = (const float4*)(stacked + (size_t)c * 256 + lprev * 64);
    float4 m = src[j];
    float* dst = stacked + (size_t)r * 256 + (lprev + 1) * 64 + j * 4;
    atomicAdd(dst + 0, v * m.x); atomicAdd(dst + 1, v * m.y);
    atomicAdd(dst + 2, v * m.z); atomicAdd(dst + 3, v * m.w);
}

__global__ void mean_layers_plain(const float* __restrict__ stacked, float* __restrict__ meanOut) {
    int t = blockIdx.x * blockDim.x + threadIdx.x;
    if (t >= N_NODES * 16) return;
    int n = t >> 4, j = t & 15;
    const float4* base = (const float4*)(stacked + (size_t)n * 256);
    float4 a = base[j], b = base[16 + j], c = base[32 + j], d = base[48 + j];
    float4 s;
    s.x = 0.25f * (a.x + b.x + c.x + d.x);
    s.y = 0.25f * (a.y + b.y + c.y + d.y);
    s.z = 0.25f * (a.z + b.z + c.z + d.z);
    s.w = 0.25f * (a.w + b.w + c.w + d.w);
    ((float4*)meanOut)[t] = s;
}

extern "C" void kernel_launch(void* const* d_in, const int* in_sizes, int n_in,
                              void* d_out, int out_size, void* d_ws, size_t ws_size,
                              hipStream_t stream) {
    const float* emb  = (const float*)d_in[0];
    const int*   rows = (const int*)d_in[1];
    const int*   cols = (const int*)d_in[2];
    const float* vals = (const float*)d_in[3];

    float* meanOut = (float*)d_out;
    float* stacked = (float*)d_out + (size_t)N_NODES * EMB_DIM;

    size_t need_fused = (size_t)(3 * NBINS + 1) * sizeof(int) + 64
                      + (size_t)N_EDGES * sizeof(uint2)
                      + (size_t)N_NODES * EMB_DIM * sizeof(unsigned short);
    const size_t headInts = (size_t)(N_NODES * 2 + 1 + 2 * N_SCAN_BLOCKS);
    size_t need_f32 = headInts * sizeof(int) + 64 + (size_t)N_EDGES * sizeof(int2);

    if (ws_size >= need_fused) {
        char* w = (char*)d_ws;
        int* binCounts  = (int*)w;                 // NBINS
        int* bucketFill = binCounts + NBINS;       // NBINS
        int* binPtr     = binCounts + 2 * NBINS;   // NBINS + 1
        w += (size_t)(3 * NBINS + 1) * sizeof(int);
        w = (char*)(((uintptr_t)w + 15) & ~(uintptr_t)15);
        uint2* records = (uint2*)w;  w += (size_t)N_EDGES * sizeof(uint2);
        unsigned short* mirrorA = (unsigned short*)w;
        // mirrorB lives in the mean region of d_out: written by spmm1, read by
        // spmm2, dead before spmm_last writes mean (kernel-serialized).
        unsigned short* mirrorB = (unsigned short*)meanOut;

        hipMemsetAsync(binCounts, 0, (size_t)(2 * NBINS) * sizeof(int), stream);
        bin_count<<<BC_WGS, 256, 0, stream>>>(rows, binCounts);
        bin_scan<<<1, 1024, 0, stream>>>(binCounts, binPtr);
        build_sort2<<<NCHUNKS, 256, 0, stream>>>(rows, cols, vals, binPtr, bucketFill, records);
        {
            int total = N_NODES * 16;
            int grid = (total + 255) / 256;
            emb_to_bf16<<<grid, 256, 0, stream>>>(emb, (ushort4*)mirrorA);
        }
        spmm_bin_mid<<<SPMM_GRID, 256, 0, stream>>>(binPtr, records, mirrorA, stacked + 1 * 64, mirrorB);
        spmm_bin_mid<<<SPMM_GRID, 256, 0, stream>>>(binPtr, records, mirrorB, stacked + 2 * 64, mirrorA);
        spmm_bin_last<<<SPMM_GRID, 256, 0, stream>>>(binPtr, records, mirrorA, emb, stacked, meanOut);
    } else if (ws_size >= need_f32) {
        char* w = (char*)d_ws;
        int* counts    = (int*)w;  w += (size_t)N_NODES * sizeof(int);
        int* row_ptr   = (int*)w;  w += (size_t)(N_NODES + 1) * sizeof(int);
        int* blockSums = (int*)w;  w += (size_t)N_SCAN_BLOCKS * sizeof(int);
        int* blockOffs = (int*)w;  w += (size_t)N_SCAN_BLOCKS * sizeof(int);
        w = (char*)(((uintptr_t)w + 15) & ~(uintptr_t)15);
        int2* s_colval = (int2*)w;

        hipMemsetAsync(counts, 0, (size_t)N_NODES * sizeof(int), stream);
        {
            int block = 256, grid = (N_EDGES + block - 1) / block;
            count_rows<<<grid, block, 0, stream>>>(rows, counts);
        }
        scan_phase1<<<N_SCAN_BLOCKS, SCAN_BLOCK, 0, stream>>>(counts, blockSums);
        scan_phase2<<<1, 256, 0, stream>>>(blockSums, blockOffs, row_ptr);
        scan_phase3<<<N_SCAN_BLOCKS, SCAN_BLOCK, 0, stream>>>(counts, blockOffs, row_ptr);
        hipMemsetAsync(counts, 0, (size_t)N_NODES * sizeof(int), stream);
        {
            int block = 256, grid = (N_EDGES + block - 1) / block;
            scatter_edges_int2<<<grid, block, 0, stream>>>(rows, cols, vals, row_ptr, counts, s_colval);
        }
        {
            long long threads = (long long)N_NODES * 64;
            int block = 256;
            int grid = (int)((threads + block - 1) / block);
            spmm_gather_f32<<<grid, block, 0, stream>>>(row_ptr, s_colval, emb, 64, stacked + 1 * 64);
            spmm_gather_f32<<<grid, block, 0, stream>>>(row_ptr, s_colval, stacked + 1 * 64, 256, stacked + 2 * 64);
            spmm_gather_f32<<<grid, block, 0, stream>>>(row_ptr, s_colval, stacked + 2 * 64, 256, stacked + 3 * 64);
        }
        {
            int total = N_NODES * 16;
            int block = 256, grid = (total + block - 1) / block;
            mean_layers<<<grid, block, 0, stream>>>(emb, stacked, meanOut);
        }
    } else {
        {
            int total = N_NODES * 64;
            int block = 256, grid = (total + block - 1) / block;
            init_stacked_full<<<grid, block, 0, stream>>>(emb, stacked);
        }
        {
            long long total = (long long)N_EDGES * 16;
            int block = 256, grid = (int)((total + block - 1) / block);
            for (int l = 0; l < N_LAYERS; ++l)
                spmm_atomic<<<grid, block, 0, stream>>>(rows, cols, vals, stacked, l);
        }
        {
            int total = N_NODES * 16;
            int block = 256, grid = (total + block - 1) / block;
            mean_layers_plain<<<grid, block, 0, stream>>>(stacked, meanOut);
        }
    }
}

// Round 8
// 572.862 us; speedup vs baseline: 6.6355x; 6.6355x over previous
//
#include <hip/hip_runtime.h>
#include <hip/hip_fp16.h>

#define N_NODES 100000
#define EMB_DIM 64
#define N_EDGES 3200000
#define N_LAYERS 3

#define SCAN_BLOCK 512
#define N_SCAN_BLOCKS ((N_NODES + SCAN_BLOCK - 1) / SCAN_BLOCK)   // 196

// Coarse bins for the two-phase CSR build.
#define ABINROWS 256
#define NBINS ((N_NODES + ABINROWS - 1) / ABINROWS)   // 391
#define NBINS_P 512
#define ACHUNK 2048
#define AEPT 8
#define NCHUNKS ((N_EDGES + ACHUNK - 1) / ACHUNK)     // 1563
#define BCHUNK 4096
#define NBCHUNKS ((N_EDGES + BCHUNK - 1) / BCHUNK)    // 782

// d_out layout: mean [N_NODES*64] first, then stacked [N_NODES*4*64]
// stacked[n][l][d] at n*256 + l*64 + d

typedef float f32x4 __attribute__((ext_vector_type(4)));
typedef unsigned short u16x4 __attribute__((ext_vector_type(4)));

__device__ __forceinline__ unsigned short f32_to_bf16_rtn(float f) {
    unsigned u = __float_as_uint(f);
    unsigned r = u + 0x7FFFu + ((u >> 16) & 1u);
    return (unsigned short)(r >> 16);
}
__device__ __forceinline__ float bf16_to_f32(unsigned short h) {
    return __uint_as_float(((unsigned)h) << 16);
}

// ---------- bin-level counting (no per-row global atomics) ----------

__global__ void __launch_bounds__(256) bin_count(const int* __restrict__ rows,
                                                 int* __restrict__ binCounts) {
    __shared__ int h[NBINS];
    int t = threadIdx.x;
    for (int i = t; i < NBINS; i += 256) h[i] = 0;
    __syncthreads();
    int base = blockIdx.x * BCHUNK;
    int n = N_EDGES - base; if (n > BCHUNK) n = BCHUNK;
    for (int i = t; i < n; i += 256)
        atomicAdd(&h[__builtin_nontemporal_load(rows + base + i) >> 8], 1);
    __syncthreads();
    for (int i = t; i < NBINS; i += 256) {
        int c = h[i];
        if (c) atomicAdd(&binCounts[i], c);
    }
}

__global__ void __launch_bounds__(512) bin_scan(const int* __restrict__ binCounts,
                                                int* __restrict__ binPtr) {
    __shared__ int sm[512];
    int t = threadIdx.x;
    int v = (t < NBINS) ? binCounts[t] : 0;
    sm[t] = v;
    __syncthreads();
    for (int off = 1; off < 512; off <<= 1) {
        int u = (t >= off) ? sm[t - off] : 0;
        __syncthreads();
        sm[t] += u;
        __syncthreads();
    }
    if (t < NBINS) binPtr[t + 1] = sm[t];
    if (t == 0) binPtr[0] = 0;
}

// ---------- legacy per-row count + scan (f32 fallback path only) ----------

__global__ void count_rows(const int* __restrict__ rows, int* __restrict__ counts) {
    int e = blockIdx.x * blockDim.x + threadIdx.x;
    if (e >= N_EDGES) return;
    atomicAdd(&counts[rows[e]], 1);
}

__global__ void __launch_bounds__(SCAN_BLOCK) scan_phase1(const int* __restrict__ counts,
                                                          int* __restrict__ blockSums) {
    __shared__ int sm[SCAN_BLOCK];
    int idx = blockIdx.x * SCAN_BLOCK + threadIdx.x;
    int v = (idx < N_NODES) ? counts[idx] : 0;
    sm[threadIdx.x] = v;
    __syncthreads();
    for (int off = SCAN_BLOCK / 2; off > 0; off >>= 1) {
        if (threadIdx.x < off) sm[threadIdx.x] += sm[threadIdx.x + off];
        __syncthreads();
    }
    if (threadIdx.x == 0) blockSums[blockIdx.x] = sm[0];
}

__global__ void __launch_bounds__(256) scan_phase2(const int* __restrict__ blockSums,
                                                   int* __restrict__ blockOffs,
                                                   int* __restrict__ row_ptr) {
    __shared__ int sm[256];
    int t = threadIdx.x;
    int v = (t < N_SCAN_BLOCKS) ? blockSums[t] : 0;
    sm[t] = v;
    __syncthreads();
    for (int off = 1; off < 256; off <<= 1) {
        int u = (t >= off) ? sm[t - off] : 0;
        __syncthreads();
        sm[t] += u;
        __syncthreads();
    }
    if (t < N_SCAN_BLOCKS) blockOffs[t] = (t == 0) ? 0 : sm[t - 1];
    if (t == 255) row_ptr[N_NODES] = sm[255];
}

__global__ void __launch_bounds__(SCAN_BLOCK) scan_phase3(const int* __restrict__ counts,
                                                          const int* __restrict__ blockOffs,
                                                          int* __restrict__ row_ptr) {
    __shared__ int sm[SCAN_BLOCK];
    int idx = blockIdx.x * SCAN_BLOCK + threadIdx.x;
    int t = threadIdx.x;
    int v = (idx < N_NODES) ? counts[idx] : 0;
    sm[t] = v;
    __syncthreads();
    for (int off = 1; off < SCAN_BLOCK; off <<= 1) {
        int u = (t >= off) ? sm[t - off] : 0;
        __syncthreads();
        sm[t] += u;
        __syncthreads();
    }
    if (idx < N_NODES) row_ptr[idx] = blockOffs[blockIdx.x] + sm[t] - v;
}

// ---------- phase A: LDS counting-sort partition (dense run writes) ----------
// Packed edge: col (17 bits) << 15 | fp16(val) low 15 bits (val>=0 so sign=0).

__global__ void __launch_bounds__(256) build_sortA(const int* __restrict__ rows,
                                                   const int* __restrict__ cols,
                                                   const float* __restrict__ vals,
                                                   const int* __restrict__ binPtr,
                                                   int* __restrict__ bucketFill,
                                                   uint2* __restrict__ records) {
    __shared__ int binCnt[NBINS_P];
    __shared__ int binInc[NBINS_P];   // inclusive prefix of binCnt
    __shared__ int binCur[NBINS_P];
    __shared__ int binG[NBINS];       // global dst base of this WG's run per bin
    __shared__ uint2 buf[ACHUNK];     // bin-sorted records

    int base = blockIdx.x * ACHUNK;
    int n = N_EDGES - base; if (n > ACHUNK) n = ACHUNK;
    int t = threadIdx.x;

    for (int i = t; i < NBINS_P; i += 256) { binCnt[i] = 0; binCur[i] = 0; }
    __syncthreads();

    // Load AEPT edges/thread (static unroll -> registers) + histogram.
    int r_[AEPT]; unsigned pk_[AEPT];
#pragma unroll AEPT
    for (int k = 0; k < AEPT; ++k) {
        int i = t + k * 256;
        r_[k] = 0; pk_[k] = 0;
        if (i < n) {
            int e = base + i;
            int r = __builtin_nontemporal_load(rows + e);
            unsigned hb = __half_as_ushort(__float2half(__builtin_nontemporal_load(vals + e)));
            r_[k] = r;
            pk_[k] = (((unsigned)__builtin_nontemporal_load(cols + e)) << 15) | (hb & 0x7FFFu);
            atomicAdd(&binCnt[r >> 8], 1);
        }
    }
    __syncthreads();

    // Hillis-Steele inclusive scan over NBINS_P entries (2 per thread).
    binInc[t] = binCnt[t];
    binInc[t + 256] = binCnt[t + 256];
    __syncthreads();
    for (int off = 1; off < NBINS_P; off <<= 1) {
        int i0 = t, i1 = t + 256;
        int v0 = (i0 >= off) ? binInc[i0 - off] : 0;
        int v1 = (i1 >= off) ? binInc[i1 - off] : 0;
        __syncthreads();
        binInc[i0] += v0;
        binInc[i1] += v1;
        __syncthreads();
    }

    // Scatter records into LDS at bin-sorted positions.
#pragma unroll AEPT
    for (int k = 0; k < AEPT; ++k) {
        int i = t + k * 256;
        if (i < n) {
            int b = r_[k] >> 8;
            int slot = (binInc[b] - binCnt[b]) + atomicAdd(&binCur[b], 1);
            buf[slot] = make_uint2((unsigned)r_[k], pk_[k]);
        }
    }
    // One global reservation per non-empty bin.
    for (int b = t; b < NBINS; b += 256) {
        int c = binCnt[b];
        if (c > 0) binG[b] = binPtr[b] + atomicAdd(&bucketFill[b], c);
    }
    __syncthreads();

    // Coalesced copy-out: consecutive p within a run -> consecutive global dst.
    for (int p = t; p < n; p += 256) {
        uint2 rec = buf[p];
        int b = (int)(rec.x >> 8);
        int dst = binG[b] + (p - (binInc[b] - binCnt[b]));
        records[dst] = rec;
    }
}

// ---------- phase B: per-bin row_ptr derivation + scatter to exact CSR slots ----------
__global__ void __launch_bounds__(256) build_phaseB(const int* __restrict__ binPtr,
                                                    const uint2* __restrict__ records,
                                                    unsigned* __restrict__ s_edges,
                                                    int* __restrict__ row_ptr) {
    __shared__ int lcnt[ABINROWS];
    __shared__ int linc[ABINROWS];
    __shared__ int lrp[ABINROWS];
    __shared__ int lfill[ABINROWS];
    int b = blockIdx.x;
    int t = threadIdx.x;
    int r0 = b * ABINROWS;
    int r1 = r0 + ABINROWS; if (r1 > N_NODES) r1 = N_NODES;
    int nr = r1 - r0;
    int beg = binPtr[b];
    int end = binPtr[b + 1];

    lcnt[t] = 0; lfill[t] = 0;
    __syncthreads();
    // Pass 1: per-row histogram.
    for (int i = beg + t; i < end; i += 256) {
        atomicAdd(&lcnt[(int)records[i].x - r0], 1);
    }
    __syncthreads();
    // Inclusive scan of 256 entries.
    linc[t] = lcnt[t];
    __syncthreads();
    for (int off = 1; off < 256; off <<= 1) {
        int u = (t >= off) ? linc[t - off] : 0;
        __syncthreads();
        linc[t] += u;
        __syncthreads();
    }
    lrp[t] = beg + linc[t] - lcnt[t];   // exclusive prefix + bin base
    if (t < nr) row_ptr[r0 + t] = lrp[t];
    if (t == 0) row_ptr[r0 + nr] = end;
    __syncthreads();
    // Pass 2: scatter (records re-read is L2-resident).
    for (int i = beg + t; i < end; i += 256) {
        uint2 rec = records[i];
        int lr = (int)rec.x - r0;
        int lp = atomicAdd(&lfill[lr], 1);
        s_edges[lrp[lr] + lp] = rec.y;
    }
}

// ---------- emb -> bf16 mirror (pure stream: nt both sides) ----------
__global__ void emb_to_bf16(const float* __restrict__ emb, unsigned short* __restrict__ mirror) {
    int t = blockIdx.x * blockDim.x + threadIdx.x;   // [0, N_NODES*16)
    if (t >= N_NODES * 16) return;
    f32x4 v = __builtin_nontemporal_load((const f32x4*)emb + t);
    u16x4 o;
    o.x = f32_to_bf16_rtn(v.x); o.y = f32_to_bf16_rtn(v.y);
    o.z = f32_to_bf16_rtn(v.z); o.w = f32_to_bf16_rtn(v.w);
    __builtin_nontemporal_store(o, (u16x4*)mirror + t);
}

// ---------- SpMM gather core, bf16 source: one wave per destination node ----------
// 4 groups x 16 lanes; lane j of a group owns bf16x4 chunk j of the 64-dim row.
// Edge words staged via ONE coalesced per-lane load (non-temporal: no reuse,
// keep L2 for the mirror gather table), distributed with __shfl.
// Mirror gathers use normal cached loads (the only data with reuse).
// Control flow is wave-uniform (shfl from inactive lanes is undefined on CDNA).

__device__ __forceinline__ void gacc(float4& acc, unsigned p, int j,
                                     const unsigned short* __restrict__ srcMirror) {
    float v = __half2float(__ushort_as_half((unsigned short)(p & 0x7FFFu)));
    ushort4 m = *(const ushort4*)(srcMirror + (size_t)(p >> 15) * 64 + j * 4);
    acc.x += v * bf16_to_f32(m.x);
    acc.y += v * bf16_to_f32(m.y);
    acc.z += v * bf16_to_f32(m.z);
    acc.w += v * bf16_to_f32(m.w);
}

__device__ __forceinline__ float4 spmm_row_core(int beg, int end, int g, int j, int lane,
                                                const unsigned* __restrict__ s_edges,
                                                const unsigned short* __restrict__ srcMirror) {
    int deg = end - beg;                  // wave-uniform
    unsigned ew = (lane < deg) ? __builtin_nontemporal_load(s_edges + beg + lane) : 0u;
    float4 acc = make_float4(0.f, 0.f, 0.f, 0.f);
    int nfull = deg < 64 ? deg : 64;      // wave-uniform
    for (int kb = 0; kb < nfull; kb += 16) {
        int k0 = kb + g, k1 = kb + g + 4, k2 = kb + g + 8, k3 = kb + g + 12;
        unsigned p0 = __shfl(ew, k0);
        unsigned p1 = __shfl(ew, k1);
        unsigned p2 = __shfl(ew, k2);
        unsigned p3 = __shfl(ew, k3);
        if (k0 < nfull) gacc(acc, p0, j, srcMirror);
        if (k1 < nfull) gacc(acc, p1, j, srcMirror);
        if (k2 < nfull) gacc(acc, p2, j, srcMirror);
        if (k3 < nfull) gacc(acc, p3, j, srcMirror);
    }
    for (int e = beg + 64 + g; e < end; e += 4) {
        unsigned p = s_edges[e];
        gacc(acc, p, j, srcMirror);
    }
    acc.x += __shfl_xor(acc.x, 16); acc.y += __shfl_xor(acc.y, 16);
    acc.z += __shfl_xor(acc.z, 16); acc.w += __shfl_xor(acc.w, 16);
    acc.x += __shfl_xor(acc.x, 32); acc.y += __shfl_xor(acc.y, 32);
    acc.z += __shfl_xor(acc.z, 32); acc.w += __shfl_xor(acc.w, 32);
    return acc;
}

__global__ void __launch_bounds__(256) spmm_gather_bf16_mid(const int* __restrict__ row_ptr,
                                                            const unsigned* __restrict__ s_edges,
                                                            const unsigned short* __restrict__ srcMirror,
                                                            float* __restrict__ dstStacked,
                                                            unsigned short* __restrict__ dstMirror) {
    int wave = (blockIdx.x * blockDim.x + threadIdx.x) >> 6;
    if (wave >= N_NODES) return;
    int lane = threadIdx.x & 63;
    int g = lane >> 4, j = lane & 15;
    float4 acc = spmm_row_core(row_ptr[wave], row_ptr[wave + 1], g, j, lane, s_edges, srcMirror);
    if (lane < 16) {
        f32x4 vv = {acc.x, acc.y, acc.z, acc.w};
        __builtin_nontemporal_store(vv, (f32x4*)(dstStacked + (size_t)wave * 256 + j * 4));
        u16x4 o;
        o.x = f32_to_bf16_rtn(acc.x); o.y = f32_to_bf16_rtn(acc.y);
        o.z = f32_to_bf16_rtn(acc.z); o.w = f32_to_bf16_rtn(acc.w);
        __builtin_nontemporal_store(o, (u16x4*)(dstMirror + (size_t)wave * 64 + j * 4));
    }
}

// Last layer: fuse the 4-layer mean + layer-0 copy into the same dispatch.
// All stream reads/writes non-temporal; only mirror gathers stay cached.
__global__ void __launch_bounds__(256) spmm_gather_bf16_last(const int* __restrict__ row_ptr,
                                                             const unsigned* __restrict__ s_edges,
                                                             const unsigned short* __restrict__ srcMirror,
                                                             const float* __restrict__ emb,
                                                             float* __restrict__ stacked,
                                                             float* __restrict__ meanOut) {
    int wave = (blockIdx.x * blockDim.x + threadIdx.x) >> 6;
    if (wave >= N_NODES) return;
    int lane = threadIdx.x & 63;
    int g = lane >> 4, j = lane & 15;
    float4 acc = spmm_row_core(row_ptr[wave], row_ptr[wave + 1], g, j, lane, s_edges, srcMirror);
    if (lane < 16) {
        float* base = stacked + (size_t)wave * 256 + j * 4;
        f32x4 a  = __builtin_nontemporal_load((const f32x4*)(emb + (size_t)wave * 64 + j * 4));
        f32x4 b1 = __builtin_nontemporal_load((const f32x4*)(base + 64));
        f32x4 c2 = __builtin_nontemporal_load((const f32x4*)(base + 128));
        f32x4 d3 = {acc.x, acc.y, acc.z, acc.w};
        __builtin_nontemporal_store(a, (f32x4*)base);            // layer 0
        __builtin_nontemporal_store(d3, (f32x4*)(base + 192));   // layer 3
        f32x4 s;
        s.x = 0.25f * (a.x + b1.x + c2.x + d3.x);
        s.y = 0.25f * (a.y + b1.y + c2.y + d3.y);
        s.z = 0.25f * (a.z + b1.z + c2.z + d3.z);
        s.w = 0.25f * (a.w + b1.w + c2.w + d3.w);
        __builtin_nontemporal_store(s, (f32x4*)(meanOut + (size_t)wave * 64 + j * 4));
    }
}

// ---------- mean over 4 layers (f32 fallback path) ----------
__global__ void mean_layers(const float* __restrict__ emb,
                            float* __restrict__ stacked,
                            float* __restrict__ meanOut) {
    int t = blockIdx.x * blockDim.x + threadIdx.x;   // [0, N_NODES*16)
    if (t >= N_NODES * 16) return;
    int n = t >> 4;
    int j = t & 15;
    float4* base = (float4*)stacked + (size_t)n * 64;
    float4 a = ((const float4*)emb)[t];
    float4 b = base[16 + j];
    float4 c = base[32 + j];
    float4 d = base[48 + j];
    base[j] = a;
    float4 s;
    s.x = 0.25f * (a.x + b.x + c.x + d.x);
    s.y = 0.25f * (a.y + b.y + c.y + d.y);
    s.z = 0.25f * (a.z + b.z + c.z + d.z);
    s.w = 0.25f * (a.w + b.w + c.w + d.w);
    ((float4*)meanOut)[t] = s;
}

// ---------- mid fallback: fp32 CSR gather ----------

__global__ void scatter_edges_int2(const int* __restrict__ rows, const int* __restrict__ cols,
                                   const float* __restrict__ vals,
                                   const int* __restrict__ row_ptr, int* __restrict__ fill,
                                   int2* __restrict__ s_colval) {
    int e = blockIdx.x * blockDim.x + threadIdx.x;
    if (e >= N_EDGES) return;
    int r = rows[e];
    int pos = row_ptr[r] + atomicAdd(&fill[r], 1);
    int2 p; p.x = cols[e]; p.y = __float_as_int(vals[e]);
    s_colval[pos] = p;
}

__global__ void __launch_bounds__(256) spmm_gather_f32(const int* __restrict__ row_ptr,
                                                       const int2* __restrict__ s_colval,
                                                       const float* __restrict__ src, int srcStride,
                                                       float* __restrict__ dst) {
    int wave = (blockIdx.x * blockDim.x + threadIdx.x) >> 6;
    if (wave >= N_NODES) return;
    int lane = threadIdx.x & 63;
    int g = lane >> 4, j = lane & 15;
    int beg = row_ptr[wave], end = row_ptr[wave + 1];
    float4 acc = make_float4(0.f, 0.f, 0.f, 0.f);
    int e = beg + g;
    for (; e + 4 < end; e += 8) {
        int2 p0 = s_colval[e], p1 = s_colval[e + 4];
        float v0 = __int_as_float(p0.y), v1 = __int_as_float(p1.y);
        float4 m0 = *(const float4*)(src + (size_t)p0.x * srcStride + j * 4);
        float4 m1 = *(const float4*)(src + (size_t)p1.x * srcStride + j * 4);
        acc.x += v0 * m0.x + v1 * m1.x; acc.y += v0 * m0.y + v1 * m1.y;
        acc.z += v0 * m0.z + v1 * m1.z; acc.w += v0 * m0.w + v1 * m1.w;
    }
    for (; e < end; e += 4) {
        int2 p = s_colval[e];
        float v = __int_as_float(p.y);
        float4 m = *(const float4*)(src + (size_t)p.x * srcStride + j * 4);
        acc.x += v * m.x; acc.y += v * m.y; acc.z += v * m.z; acc.w += v * m.w;
    }
    acc.x += __shfl_xor(acc.x, 16); acc.y += __shfl_xor(acc.y, 16);
    acc.z += __shfl_xor(acc.z, 16); acc.w += __shfl_xor(acc.w, 16);
    acc.x += __shfl_xor(acc.x, 32); acc.y += __shfl_xor(acc.y, 32);
    acc.z += __shfl_xor(acc.z, 32); acc.w += __shfl_xor(acc.w, 32);
    if (lane < 16)
        *(float4*)(dst + (size_t)wave * 256 + j * 4) = acc;
}

// ---------- last fallback: atomic scatter ----------

__global__ void init_stacked_full(const float* __restrict__ emb, float* __restrict__ stacked) {
    int t = blockIdx.x * blockDim.x + threadIdx.x;
    if (t >= N_NODES * 64) return;
    int n = t >> 6, j = t & 63;
    float4 v = (j < 16) ? ((const float4*)emb)[n * 16 + j] : make_float4(0.f, 0.f, 0.f, 0.f);
    ((float4*)stacked)[n * 64 + j] = v;
}

__global__ void spmm_atomic(const int* __restrict__ rows, const int* __restrict__ cols,
                            const float* __restrict__ vals, float* __restrict__ stacked,
                            int lprev) {
    int t = blockIdx.x * blockDim.x + threadIdx.x;
    int e = t >> 4, j = t & 15;
    if (e >= N_EDGES) return;
    int r = rows[e], c = cols[e];
    float v = vals[e];
    const float4* src = (const float4*)(stacked + (size_t)c * 256 + lprev * 64);
    float4 m = src[j];
    float* dst = stacked + (size_t)r * 256 + (lprev + 1) * 64 + j * 4;
    atomicAdd(dst + 0, v * m.x); atomicAdd(dst + 1, v * m.y);
    atomicAdd(dst + 2, v * m.z); atomicAdd(dst + 3, v * m.w);
}

__global__ void mean_layers_plain(const float* __restrict__ stacked, float* __restrict__ meanOut) {
    int t = blockIdx.x * blockDim.x + threadIdx.x;
    if (t >= N_NODES * 16) return;
    int n = t >> 4, j = t & 15;
    const float4* base = (const float4*)(stacked + (size_t)n * 256);
    float4 a = base[j], b = base[16 + j], c = base[32 + j], d = base[48 + j];
    float4 s;
    s.x = 0.25f * (a.x + b.x + c.x + d.x);
    s.y = 0.25f * (a.y + b.y + c.y + d.y);
    s.z = 0.25f * (a.z + b.z + c.z + d.z);
    s.w = 0.25f * (a.w + b.w + c.w + d.w);
    ((float4*)meanOut)[t] = s;
}

extern "C" void kernel_launch(void* const* d_in, const int* in_sizes, int n_in,
                              void* d_out, int out_size, void* d_ws, size_t ws_size,
                              hipStream_t stream) {
    const float* emb  = (const float*)d_in[0];
    const int*   rows = (const int*)d_in[1];
    const int*   cols = (const int*)d_in[2];
    const float* vals = (const float*)d_in[3];

    float* meanOut = (float*)d_out;
    float* stacked = (float*)d_out + (size_t)N_NODES * EMB_DIM;

    const size_t headInts = (size_t)(N_NODES * 2 + 1 + 2 * N_SCAN_BLOCKS);
    size_t need_bf16 = headInts * sizeof(int) + 64
                     + (size_t)N_EDGES * sizeof(unsigned)
                     + 2 * (size_t)N_NODES * EMB_DIM * sizeof(unsigned short);
    size_t need_f32  = headInts * sizeof(int) + 64 + (size_t)N_EDGES * sizeof(int2);

    if (ws_size >= need_bf16) {
        char* w = (char*)d_ws;
        int* counts    = (int*)w;  w += (size_t)N_NODES * sizeof(int);
        int* row_ptr   = (int*)w;  w += (size_t)(N_NODES + 1) * sizeof(int);
        int* blockSums = (int*)w;  w += (size_t)N_SCAN_BLOCKS * sizeof(int);
        int* blockOffs = (int*)w;  w += (size_t)N_SCAN_BLOCKS * sizeof(int);
        w = (char*)(((uintptr_t)w + 15) & ~(uintptr_t)15);
        unsigned* s_edges = (unsigned*)w;  w += (size_t)N_EDGES * sizeof(unsigned);
        unsigned short* mirrorA = (unsigned short*)w;  w += (size_t)N_NODES * EMB_DIM * sizeof(unsigned short);
        unsigned short* mirrorB = (unsigned short*)w;
        // Phase-A record staging aliases mirrorA+mirrorB (3.2M * 8B = 25.6 MB).
        // Mirrors are written only AFTER the build consumes records.
        uint2* records = (uint2*)mirrorA;
        // Bin-level arrays live in the (otherwise unused) counts region.
        int* binCounts  = counts;                 // NBINS
        int* bucketFill = counts + NBINS;         // NBINS
        int* binPtr     = counts + 2 * NBINS;     // NBINS+1

        hipMemsetAsync(counts, 0, (size_t)(2 * NBINS) * sizeof(int), stream);
        bin_count<<<NBCHUNKS, 256, 0, stream>>>(rows, binCounts);
        bin_scan<<<1, 512, 0, stream>>>(binCounts, binPtr);
        build_sortA<<<NCHUNKS, 256, 0, stream>>>(rows, cols, vals, binPtr, bucketFill, records);
        build_phaseB<<<NBINS, 256, 0, stream>>>(binPtr, records, s_edges, row_ptr);
        {
            int total = N_NODES * 16;
            int block = 256, grid = (total + block - 1) / block;
            emb_to_bf16<<<grid, block, 0, stream>>>(emb, mirrorA);
        }
        {
            long long threads = (long long)N_NODES * 64;
            int block = 256;
            int grid = (int)((threads + block - 1) / block);
            spmm_gather_bf16_mid<<<grid, block, 0, stream>>>(row_ptr, s_edges, mirrorA, stacked + 1 * 64, mirrorB);
            spmm_gather_bf16_mid<<<grid, block, 0, stream>>>(row_ptr, s_edges, mirrorB, stacked + 2 * 64, mirrorA);
            spmm_gather_bf16_last<<<grid, block, 0, stream>>>(row_ptr, s_edges, mirrorA, emb, stacked, meanOut);
        }
    } else if (ws_size >= need_f32) {
        char* w = (char*)d_ws;
        int* counts    = (int*)w;  w += (size_t)N_NODES * sizeof(int);
        int* row_ptr   = (int*)w;  w += (size_t)(N_NODES + 1) * sizeof(int);
        int* blockSums = (int*)w;  w += (size_t)N_SCAN_BLOCKS * sizeof(int);
        int* blockOffs = (int*)w;  w += (size_t)N_SCAN_BLOCKS * sizeof(int);
        w = (char*)(((uintptr_t)w + 15) & ~(uintptr_t)15);
        int2* s_colval = (int2*)w;

        hipMemsetAsync(counts, 0, (size_t)N_NODES * sizeof(int), stream);
        {
            int block = 256, grid = (N_EDGES + block - 1) / block;
            count_rows<<<grid, block, 0, stream>>>(rows, counts);
        }
        scan_phase1<<<N_SCAN_BLOCKS, SCAN_BLOCK, 0, stream>>>(counts, blockSums);
        scan_phase2<<<1, 256, 0, stream>>>(blockSums, blockOffs, row_ptr);
        scan_phase3<<<N_SCAN_BLOCKS, SCAN_BLOCK, 0, stream>>>(counts, blockOffs, row_ptr);
        hipMemsetAsync(counts, 0, (size_t)N_NODES * sizeof(int), stream);
        {
            int block = 256, grid = (N_EDGES + block - 1) / block;
            scatter_edges_int2<<<grid, block, 0, stream>>>(rows, cols, vals, row_ptr, counts, s_colval);
        }
        {
            long long threads = (long long)N_NODES * 64;
            int block = 256;
            int grid = (int)((threads + block - 1) / block);
            spmm_gather_f32<<<grid, block, 0, stream>>>(row_ptr, s_colval, emb, 64, stacked + 1 * 64);
            spmm_gather_f32<<<grid, block, 0, stream>>>(row_ptr, s_colval, stacked + 1 * 64, 256, stacked + 2 * 64);
            spmm_gather_f32<<<grid, block, 0, stream>>>(row_ptr, s_colval, stacked + 2 * 64, 256, stacked + 3 * 64);
        }
        {
            int total = N_NODES * 16;
            int block = 256, grid = (total + block - 1) / block;
            mean_layers<<<grid, block, 0, stream>>>(emb, stacked, meanOut);
        }
    } else {
        {
            int total = N_NODES * 64;
            int block = 256, grid = (total + block - 1) / block;
            init_stacked_full<<<grid, block, 0, stream>>>(emb, stacked);
        }
        {
            long long total = (long long)N_EDGES * 16;
            int block = 256, grid = (int)((total + block - 1) / block);
            for (int l = 0; l < N_LAYERS; ++l)
                spmm_atomic<<<grid, block, 0, stream>>>(rows, cols, vals, stacked, l);
        }
        {
            int total = N_NODES * 16;
            int block = 256, grid = (total + block - 1) / block;
            mean_layers_plain<<<grid, block, 0, stream>>>(stacked, meanOut);
        }
    }
}